// Round 4
// baseline (380.401 us; speedup 1.0000x reference)
//
#include <hip/hip_runtime.h>
#include <hip/hip_fp16.h>
#include <stdint.h>

typedef unsigned short u16;
typedef __attribute__((ext_vector_type(8))) __bf16 bf16x8;
typedef __attribute__((ext_vector_type(4))) float f32x4;

#define SEQ 2048
#define EMB 768
#define NB  8
#define LDQK (2 * EMB)    // 1536: row pitch of fused Q|K buffer

// counted waits (rule #18: sched_barrier after lgkm wait so MFMA can't hoist)
#define VMCNT(n) asm volatile("s_waitcnt vmcnt(" #n ")" ::: "memory")
#define LGKM(n)                                            \
  do {                                                     \
    asm volatile("s_waitcnt lgkmcnt(" #n ")" ::: "memory"); \
    __builtin_amdgcn_sched_barrier(0);                     \
  } while (0)

__device__ __forceinline__ u16 f2bf(float f) {
  union { float f; uint32_t u; } a; a.f = f;
  uint32_t r = a.u + 0x7fffu + ((a.u >> 16) & 1u);
  return (u16)(r >> 16);
}
__device__ __forceinline__ float bf2f(u16 h) {
  union { uint32_t u; float f; } a; a.u = ((uint32_t)h) << 16;
  return a.f;
}

// Bijective XCD-aware block swizzle (T1). All GEMM grids here have nwg%8==0.
__device__ __forceinline__ void swz_bid(int& bx, int& by, int& bz)
{
  const int gx = gridDim.x, gy = gridDim.y;
  const int nwg = gx * gy * gridDim.z;
  const int lid = ((int)blockIdx.z * gy + (int)blockIdx.y) * gx +
                  (int)blockIdx.x;
  const int cpx = nwg >> 3;
  const int orig = (lid & 7) * cpx + (lid >> 3);
  bx = orig % gx;
  const int t = orig / gx;
  by = t % gy;
  bz = t / gy;
}

// ---------------------------------------------------------------------------
// dtype detect (1 = fp32 inputs) + bias conversion fused.
// ---------------------------------------------------------------------------
__global__ __launch_bounds__(256) void k_detect_bias(
    const u16* __restrict__ x, int* __restrict__ flag,
    const void* __restrict__ b0, const void* __restrict__ b1,
    const void* __restrict__ b2, const void* __restrict__ b3,
    float* __restrict__ biasf)
{
  const int tid = threadIdx.x;
  int bad = 0;
#pragma unroll
  for (int i = 0; i < 4; ++i) {
    const u16 h = x[(tid * 4 + i) * 2];
    const int e = (h >> 7) & 0xFF;
    bad += (e >= 160 && e <= 254) ? 1 : 0;
  }
#pragma unroll
  for (int off = 32; off > 0; off >>= 1) bad += __shfl_down(bad, off);
  __shared__ int cnt[4];
  __shared__ int sflag;
  if ((tid & 63) == 0) cnt[tid >> 6] = bad;
  __syncthreads();
  if (tid == 0) {
    const int f = (cnt[0] + cnt[1] + cnt[2] + cnt[3] > 200) ? 1 : 0;
    sflag = f;
    *flag = f;
  }
  __syncthreads();
  const int f32 = sflag;
#pragma unroll
  for (int z = 0; z < 4; ++z) {
    const void* src = (z == 0) ? b0 : (z == 1) ? b1 : (z == 2) ? b2 : b3;
#pragma unroll
    for (int i = 0; i < 3; ++i) {
      const int j = tid + i * 256;
      biasf[z * EMB + j] = f32 ? ((const float*)src)[j]
                               : bf2f(((const u16*)src)[j]);
    }
  }
}

__global__ __launch_bounds__(256) void k_convert_x(
    const void* __restrict__ src, u16* __restrict__ dst,
    const int* __restrict__ flag, int n4)
{
  const int i = blockIdx.x * 256 + threadIdx.x;
  if (i >= n4) return;
  if (*flag) {
    const float4 f = ((const float4*)src)[i];
    ushort4 o;
    o.x = f2bf(f.x); o.y = f2bf(f.y); o.z = f2bf(f.z); o.w = f2bf(f.w);
    ((ushort4*)dst)[i] = o;
  } else {
    ((ushort4*)dst)[i] = ((const ushort4*)src)[i];
  }
}

// weights: convert + transpose -> WT (bf16).
__global__ __launch_bounds__(256) void k_transpose_w(
    const void* __restrict__ W0, const void* __restrict__ W1,
    const void* __restrict__ W2, const void* __restrict__ W3,
    u16* __restrict__ WT, const int* __restrict__ flag)
{
  __shared__ u16 t[32][33];
  const int z = blockIdx.z;
  const void* in = (z == 0) ? W0 : (z == 1) ? W1 : (z == 2) ? W2 : W3;
  u16* out = WT + (size_t)z * EMB * EMB;
  const int c0 = blockIdx.x * 32, r0 = blockIdx.y * 32;
  const int tx = threadIdx.x, ty = threadIdx.y;
  const int f32 = *flag;
#pragma unroll
  for (int i = 0; i < 4; ++i) {
    const size_t idx = (size_t)(r0 + ty + i * 8) * EMB + c0 + tx;
    t[ty + i * 8][tx] = f32 ? f2bf(((const float*)in)[idx])
                            : ((const u16*)in)[idx];
  }
  __syncthreads();
#pragma unroll
  for (int i = 0; i < 4; ++i)
    out[(size_t)(c0 + ty + i * 8) * EMB + r0 + tx] = t[tx][ty + i * 8];
}

// ---------------------------------------------------------------------------
// 8-phase MFMA GEMM (T2+T3+T4+T5), templated tile: BM = MFR*32, BN = NFR*64.
// 512 threads = 8 waves (2M x 4N); per-wave output (MFR*16) x (NFR*16).
// BK=64, double-buffered LDS. Quarter = rows x 32 kcols bf16, linear by
// chunk (global_load_lds order), source pre-swizzled s4 ^= (row>>1)&3 and
// the same XOR on ds_read (both-sides involution).
// MFMA operands SWAPPED (mfma(B,A)): D col(lane&15) = M-row, D
// row(quad*4+reg) = N-col -> each lane owns 4 CONSECUTIVE C-columns of one
// row => 8B packed stores (4x fewer store instrs than 2B scatter).
// Configs used: (8,4) 256x256, (8,3) 256x192, (6,4) 192x256.
// Counted waits per config; vmcnt never 0 in steady state.
// ---------------------------------------------------------------------------
template <int EPI, int MFR, int NFR>
__device__ __forceinline__ void gemm_core256(
    const u16* __restrict__ A, int lda,
    const u16* __restrict__ BT, int ldbt,
    void* __restrict__ Cp, int ldc,
    const float* __restrict__ biasf, const int* __restrict__ of32,
    float scale, int K, int m0, int n0)
{
  constexpr int AQ = MFR * 1024;          // u16 per A quarter (BM x 32)
  constexpr int BQ = NFR * 2048;          // u16 per B quarter (BN x 32)
  constexpr int STRIDE = 2 * AQ + 2 * BQ; // u16 per dbuf half
  __shared__ __align__(16) u16 LDSU[2 * STRIDE];
  const int tid  = threadIdx.x;
  const int lane = tid & 63;
  const int wave = tid >> 6;
  const int wm   = wave >> 2;   // 0..1
  const int wn   = wave & 3;    // 0..3
  const int lrow = lane & 15;
  const int quad = lane >> 4;
  const int NT   = K >> 6;

  auto STAGEA = [&](int t, int kh) {
    constexpr int NCH = MFR * 128;
    const int buf = t & 1;
#pragma unroll
    for (int i = 0; i < 2; ++i) {
      const int c = i * 512 + tid;
      if (NCH == 1024 || c < NCH) {
        const int row = c >> 2;
        const int ss4 = (c & 3) ^ ((row >> 1) & 3);
        const u16* g = A + (size_t)(m0 + row) * lda + t * 64 + kh * 32 + ss4 * 8;
        u16* l = LDSU + buf * STRIDE + kh * AQ + (c & ~63) * 8;
        __builtin_amdgcn_global_load_lds(
            (const __attribute__((address_space(1))) void*)g,
            (__attribute__((address_space(3))) void*)l, 16, 0, 0);
      }
    }
  };
  auto STAGEB = [&](int t, int kh) {
    constexpr int NCH = NFR * 256;
    const int buf = t & 1;
#pragma unroll
    for (int i = 0; i < 2; ++i) {
      const int c = i * 512 + tid;
      if (NCH == 1024 || c < NCH) {
        const int row = c >> 2;
        const int ss4 = (c & 3) ^ ((row >> 1) & 3);
        const u16* g = BT + (size_t)(n0 + row) * ldbt + t * 64 + kh * 32 + ss4 * 8;
        u16* l = LDSU + buf * STRIDE + 2 * AQ + kh * BQ + (c & ~63) * 8;
        __builtin_amdgcn_global_load_lds(
            (const __attribute__((address_space(1))) void*)g,
            (__attribute__((address_space(3))) void*)l, 16, 0, 0);
      }
    }
  };

  auto FRAGA = [&](int t, int kh, int row) -> bf16x8 {
    const u16* p = LDSU + (t & 1) * STRIDE + kh * AQ + row * 32 +
                   ((quad ^ ((row >> 1) & 3)) * 8);
    bf16x8 r;
    asm volatile("ds_read_b128 %0, %1"
                 : "=v"(r)
                 : "v"((const __attribute__((address_space(3))) u16*)p));
    return r;
  };
  auto FRAGB = [&](int t, int kh, int row) -> bf16x8 {
    const u16* p = LDSU + (t & 1) * STRIDE + 2 * AQ + kh * BQ + row * 32 +
                   ((quad ^ ((row >> 1) & 3)) * 8);
    bf16x8 r;
    asm volatile("ds_read_b128 %0, %1"
                 : "=v"(r)
                 : "v"((const __attribute__((address_space(3))) u16*)p));
    return r;
  };

  f32x4 acc[MFR][NFR];
#pragma unroll
  for (int m = 0; m < MFR; ++m)
#pragma unroll
    for (int n = 0; n < NFR; ++n)
#pragma unroll
      for (int r = 0; r < 4; ++r) acc[m][n][r] = 0.0f;

  bf16x8 Af0[MFR], Af1[MFR], Bf0[NFR], Bf1[NFR];

  const int arow = wm * (MFR * 16) + lrow;
  const int brow = wn * (NFR * 16) + lrow;

  // MFMA groups, SWAPPED operands: D = frag(B)·frag(A)^T => acc[m][n] holds
  // row = A-row (lane&15 side), cols = 4 consecutive N (quad*4+reg side).
  auto MG_LO = [&](bf16x8 (&Afr)[MFR], bf16x8 (&Bfr)[NFR]) {
#pragma unroll
    for (int m = 0; m < MFR; ++m)
#pragma unroll
      for (int n = 0; n < 2; ++n)
        acc[m][n] = __builtin_amdgcn_mfma_f32_16x16x32_bf16(
            Bfr[n], Afr[m], acc[m][n], 0, 0, 0);
  };
  auto MG_HI = [&](bf16x8 (&Afr)[MFR], bf16x8 (&Bfr)[NFR]) {
#pragma unroll
    for (int m = 0; m < MFR; ++m)
#pragma unroll
      for (int n = 2; n < NFR; ++n)
        acc[m][n] = __builtin_amdgcn_mfma_f32_16x16x32_bf16(
            Bfr[n], Afr[m], acc[m][n], 0, 0, 0);
  };

  // ---- prologue: stage tiles 0 and 1 fully ----
  STAGEA(0, 0); STAGEB(0, 0); STAGEA(0, 1); STAGEB(0, 1);
  STAGEA(1, 0); STAGEB(1, 0); STAGEA(1, 1); STAGEB(1, 1);
  if constexpr (MFR == 8 && NFR == 4) { VMCNT(8); } else { VMCNT(6); }
  __builtin_amdgcn_s_barrier();   // all waves' tile-0 loads landed
  // prime R(G0) of tile 0: A-k0 (MFR) + B-k0 n0,1
#pragma unroll
  for (int m = 0; m < MFR; ++m) Af0[m] = FRAGA(0, 0, arow + m * 16);
  Bf0[0] = FRAGB(0, 0, brow);
  Bf0[1] = FRAGB(0, 0, brow + 16);

  for (int u = 0; u < NT; ++u) {
    const bool s2 = (u + 2) < NT;
    // ---- q0: read B-k0 hi | stage A-k0(u+2) | MFMA G0 ----
#pragma unroll
    for (int n = 2; n < NFR; ++n) Bf0[n] = FRAGB(u, 0, brow + n * 16);
    if (s2) STAGEA(u + 2, 0);
    __builtin_amdgcn_s_barrier();
    if constexpr (NFR == 3) { LGKM(1); } else { LGKM(2); }
    __builtin_amdgcn_s_setprio(1);
    MG_LO(Af0, Bf0);
    __builtin_amdgcn_s_setprio(0);
    __builtin_amdgcn_s_barrier();
    // ---- q1: read A-k1 + B-k1 lo | stage B-k0(u+2) | MFMA G1 ----
#pragma unroll
    for (int m = 0; m < MFR; ++m) Af1[m] = FRAGA(u, 1, arow + m * 16);
    Bf1[0] = FRAGB(u, 1, brow);
    Bf1[1] = FRAGB(u, 1, brow + 16);
    if (s2) STAGEB(u + 2, 0);
    __builtin_amdgcn_s_barrier();
    if constexpr (MFR == 6) { LGKM(8); } else { LGKM(10); }
    __builtin_amdgcn_s_setprio(1);
    MG_HI(Af0, Bf0);
    __builtin_amdgcn_s_setprio(0);
    __builtin_amdgcn_s_barrier();
    // ---- q2: read B-k1 hi | stage A-k1(u+2) | MFMA G2 ----
#pragma unroll
    for (int n = 2; n < NFR; ++n) Bf1[n] = FRAGB(u, 1, brow + n * 16);
    if (s2) STAGEA(u + 2, 1);
    __builtin_amdgcn_s_barrier();
    if constexpr (NFR == 3) { LGKM(1); } else { LGKM(2); }
    __builtin_amdgcn_s_setprio(1);
    MG_LO(Af1, Bf1);
    __builtin_amdgcn_s_setprio(0);
    __builtin_amdgcn_s_barrier();
    // ---- q3: vmcnt | stage B-k1(u+2) | barrier | read next G0 | MFMA G3 ----
    if (s2) {
      if constexpr (MFR == 8 && NFR == 4)      { VMCNT(6); }
      else if constexpr (MFR == 8 && NFR == 3) { VMCNT(5); }
      else                                     { VMCNT(4); }
    } else {
      VMCNT(0);
    }
    if (s2) STAGEB(u + 2, 1);
    __builtin_amdgcn_s_barrier();              // cross-wave: u+1 in LDS
    if (u + 1 < NT) {
#pragma unroll
      for (int m = 0; m < MFR; ++m) Af0[m] = FRAGA(u + 1, 0, arow + m * 16);
      Bf0[0] = FRAGB(u + 1, 0, brow);
      Bf0[1] = FRAGB(u + 1, 0, brow + 16);
      if constexpr (MFR == 6) { LGKM(8); } else { LGKM(10); }
    } else {
      LGKM(0);
    }
    __builtin_amdgcn_s_setprio(1);
    MG_HI(Af1, Bf1);
    __builtin_amdgcn_s_setprio(0);
    __builtin_amdgcn_s_barrier();
  }

  // ---- epilogue (swapped layout): row = m-side (lane&15), 4 consecutive
  // cols = n-side (quad*4 + reg). One 8B (or 16B f32) store per fragment. ----
  const int rb = m0 + wm * (MFR * 16) + lrow;      // + m*16 per frag
  const int cb = n0 + wn * (NFR * 16) + quad * 4;  // + n*16 per frag
  if (EPI == 3) {
    u16* C = (u16*)Cp;
#pragma unroll
    for (int m = 0; m < MFR; ++m)
#pragma unroll
      for (int n = 0; n < NFR; ++n) {
        const int row = rb + m * 16;
        const int col = cb + n * 16;
        ushort4 o;
        o.x = __half_as_ushort(__float2half(acc[m][n][0] * scale));
        o.y = __half_as_ushort(__float2half(acc[m][n][1] * scale));
        o.z = __half_as_ushort(__float2half(acc[m][n][2] * scale));
        o.w = __half_as_ushort(__float2half(acc[m][n][3] * scale));
        *(ushort4*)(C + (size_t)row * ldc + col) = o;
      }
  } else if (EPI == 2) {
    u16* C = (u16*)Cp;
#pragma unroll
    for (int m = 0; m < MFR; ++m)
#pragma unroll
      for (int n = 0; n < NFR; ++n) {
        const int row = rb + m * 16;
        const int col = cb + n * 16;
        ushort4 o;
        o.x = f2bf(acc[m][n][0]); o.y = f2bf(acc[m][n][1]);
        o.z = f2bf(acc[m][n][2]); o.w = f2bf(acc[m][n][3]);
        *(ushort4*)(C + (size_t)row * ldc + col) = o;
      }
  } else if (EPI == 5) {
    // per-row bias (bias indexed by m-side row), bf16 out
    u16* C = (u16*)Cp;
#pragma unroll
    for (int m = 0; m < MFR; ++m) {
      const int row = rb + m * 16;
      const float bv = biasf[row];
#pragma unroll
      for (int n = 0; n < NFR; ++n) {
        const int col = cb + n * 16;
        ushort4 o;
        o.x = f2bf(acc[m][n][0] + bv); o.y = f2bf(acc[m][n][1] + bv);
        o.z = f2bf(acc[m][n][2] + bv); o.w = f2bf(acc[m][n][3] + bv);
        *(ushort4*)(C + (size_t)row * ldc + col) = o;
      }
    }
  } else {  // EPI == 0: per-col bias (float4 load), optional f32 out
    float4 bvv[NFR];
#pragma unroll
    for (int n = 0; n < NFR; ++n)
      bvv[n] = *(const float4*)(biasf + cb + n * 16);
    const bool f32out = (of32 != nullptr) && (*of32 != 0);
    if (f32out) {
      float* C = (float*)Cp;
#pragma unroll
      for (int m = 0; m < MFR; ++m)
#pragma unroll
        for (int n = 0; n < NFR; ++n) {
          const int row = rb + m * 16;
          const int col = cb + n * 16;
          float4 o;
          o.x = acc[m][n][0] + bvv[n].x; o.y = acc[m][n][1] + bvv[n].y;
          o.z = acc[m][n][2] + bvv[n].z; o.w = acc[m][n][3] + bvv[n].w;
          *(float4*)(C + (size_t)row * ldc + col) = o;
        }
    } else {
      u16* C = (u16*)Cp;
#pragma unroll
      for (int m = 0; m < MFR; ++m)
#pragma unroll
        for (int n = 0; n < NFR; ++n) {
          const int row = rb + m * 16;
          const int col = cb + n * 16;
          ushort4 o;
          o.x = f2bf(acc[m][n][0] + bvv[n].x);
          o.y = f2bf(acc[m][n][1] + bvv[n].y);
          o.z = f2bf(acc[m][n][2] + bvv[n].z);
          o.w = f2bf(acc[m][n][3] + bvv[n].w);
          *(ushort4*)(C + (size_t)row * ldc + col) = o;
        }
    }
  }
}

// ---- GEMM kernels --------------------------------------------------------

// Q|K projection: QK[16384][1536] = xb @ (Wq|Wk) + (bq|bk). BN=192, grid 512.
__global__ __launch_bounds__(512) void k_gemm_qk(
    const u16* __restrict__ A, const u16* __restrict__ BT,
    u16* __restrict__ QK, const float* __restrict__ biasf)
{
  int bx, by, bz; swz_bid(bx, by, bz);
  gemm_core256<0, 8, 3>(A, EMB, BT, EMB, QK, LDQK, biasf, nullptr, 1.0f, EMB,
                        by * 256, bx * 192);
}

// V^T projection: VT[b][v][seq]. BM=192 (v-dim), grid (8,4,8)=256.
__global__ __launch_bounds__(512) void k_gemm_vt(
    const u16* __restrict__ WvT, const u16* __restrict__ xb,
    u16* __restrict__ VT, const float* __restrict__ biasv)
{
  int bx, by, bz; swz_bid(bx, by, bz);
  const int b = bz;
  gemm_core256<5, 6, 4>(WvT, EMB,
                        xb + (size_t)b * SEQ * EMB, EMB,
                        VT + (size_t)b * EMB * SEQ, SEQ,
                        biasv, nullptr, 1.0f, EMB,
                        by * 192, bx * 256);
}

// output projection: d_out = O @ Wo + bo. BN=192, grid (4,64)=256.
__global__ __launch_bounds__(512) void k_gemm_out(
    const u16* __restrict__ A, const u16* __restrict__ BT,
    void* __restrict__ C, const float* __restrict__ biasf,
    const int* __restrict__ of32)
{
  int bx, by, bz; swz_bid(bx, by, bz);
  gemm_core256<0, 8, 3>(A, EMB, BT, EMB, C, EMB, biasf, of32, 1.0f, EMB,
                        by * 256, bx * 192);
}

// S[z] = Q[b] @ K[b]^T * scale  (f16 out, pitch 2048 u16). 256x256, grid 512.
__global__ __launch_bounds__(512) void k_gemm_scores(
    const u16* __restrict__ QK, u16* __restrict__ S, int b0)
{
  int bx, by, bz; swz_bid(bx, by, bz);
  const int b = b0 + bz;
  const u16* base = QK + (size_t)b * SEQ * LDQK;
  gemm_core256<3, 8, 4>(base, LDQK,              // Q
                        base + EMB, LDQK,        // K
                        S + (size_t)bz * SEQ * SEQ, SEQ,
                        nullptr, nullptr,
                        0.03608439182435161f /* 1/sqrt(768) */, EMB,
                        by * 256, bx * 256);
}

// O[b] = P[b] @ V[b]  with P bf16 (pitch 2048 u16) and VT[b] = V[b]^T.
// BN=192, grid (4,8,8)=256 = exactly 1 block/CU.
__global__ __launch_bounds__(512) void k_gemm_pv(
    const u16* __restrict__ P, const u16* __restrict__ VT,
    u16* __restrict__ O, int b0)
{
  int bx, by, bz; swz_bid(bx, by, bz);
  const int b = b0 + bz;
  gemm_core256<2, 8, 3>(P  + (size_t)bz * SEQ * SEQ, SEQ,
                        VT + (size_t)b * EMB * SEQ, SEQ,
                        O  + (size_t)b * SEQ * EMB, EMB,
                        nullptr, nullptr, 1.0f, SEQ,
                        by * 256, bx * 192);
}

// row softmax: read f16 row, write bf16 in place.
__global__ __launch_bounds__(256) void k_softmax(u16* __restrict__ S)
{
  u16* row = S + ((size_t)blockIdx.y * SEQ + blockIdx.x) * SEQ;
  const int tid = threadIdx.x;

  uint4 raw = *(const uint4*)(row + tid * 8);
  const u16* h = (const u16*)&raw;
  float v[8];
#pragma unroll
  for (int i = 0; i < 8; ++i) v[i] = __half2float(__ushort_as_half(h[i]));

  float mx = v[0];
#pragma unroll
  for (int i = 1; i < 8; ++i) mx = fmaxf(mx, v[i]);
#pragma unroll
  for (int off = 32; off > 0; off >>= 1) mx = fmaxf(mx, __shfl_down(mx, off));
  __shared__ float red[4], red2[4];
  if ((tid & 63) == 0) red[tid >> 6] = mx;
  __syncthreads();
  mx = fmaxf(fmaxf(red[0], red[1]), fmaxf(red[2], red[3]));

  float s = 0.0f;
#pragma unroll
  for (int i = 0; i < 8; ++i) { v[i] = __expf(v[i] - mx); s += v[i]; }
#pragma unroll
  for (int off = 32; off > 0; off >>= 1) s += __shfl_down(s, off);
  if ((tid & 63) == 0) red2[tid >> 6] = s;
  __syncthreads();
  s = red2[0] + red2[1] + red2[2] + red2[3];
  const float inv = 1.0f / s;

  uint4 outv;
  u16* o = (u16*)&outv;
#pragma unroll
  for (int i = 0; i < 8; ++i) o[i] = f2bf(v[i] * inv);
  *(uint4*)(row + tid * 8) = outv;
}

// ---- host launch ---------------------------------------------------------

extern "C" void kernel_launch(void* const* d_in, const int* in_sizes, int n_in,
                              void* d_out, int out_size, void* d_ws, size_t ws_size,
                              hipStream_t stream)
{
  (void)in_sizes; (void)n_in; (void)out_size;
  const void* x  = d_in[0];
  const void* Wq = d_in[1];
  const void* bq = d_in[2];
  const void* Wk = d_in[3];
  const void* bk = d_in[4];
  const void* Wv = d_in[5];
  const void* bv = d_in[6];
  const void* Wo = d_in[7];
  const void* bo = d_in[8];

  char* ws = (char*)d_ws;
  size_t off = 0;
  auto alloc = [&](size_t bytes) -> void* {
    void* p = ws + off;
    off += (bytes + 255) & ~(size_t)255;
    return p;
  };
  int*   flag  = (int*)alloc(256);
  u16*   xb    = (u16*)alloc((size_t)NB * SEQ * EMB * 2);       // 25.2 MB
  u16*   QK    = (u16*)alloc((size_t)NB * SEQ * LDQK * 2);      // 50.3 MB
  u16*   VT    = (u16*)alloc((size_t)NB * EMB * SEQ * 2);       // 25.2 MB
  u16*   O     = (u16*)alloc((size_t)NB * SEQ * EMB * 2);       // 25.2 MB
  u16*   WT    = (u16*)alloc((size_t)4 * EMB * EMB * 2);        //  4.7 MB
  float* biasf = (float*)alloc((size_t)4 * EMB * 4);
  u16*   S     = (u16*)(ws + off);                              // f16/bf16
  size_t rem   = (ws_size > off) ? ws_size - off : 0;

  int GB = 8;  // batches per S-group; shrink if workspace is tight
  while (GB > 1 && (size_t)GB * ((size_t)SEQ * SEQ * 2) > rem) GB >>= 1;

  // 0. dtype detect + bias conversion, then input normalization to bf16
  k_detect_bias<<<1, 256, 0, stream>>>((const u16*)x, flag, bq, bk, bv, bo,
                                       biasf);
  const int n4 = NB * SEQ * EMB / 4;
  k_convert_x<<<(n4 + 255) / 256, 256, 0, stream>>>(x, xb, flag, n4);
  k_transpose_w<<<dim3(EMB / 32, EMB / 32, 4), dim3(32, 8), 0, stream>>>(
      Wq, Wk, Wv, Wo, WT, flag);

  // 1a. Q|K projection (M=16384, N=1536, K=768): grid 512 = 2 full passes
  k_gemm_qk<<<dim3(8, 64), 512, 0, stream>>>(xb, WT, QK, biasf);
  // 1b. V^T projection (per batch: M=768(v), N=2048(seq), K=768): grid 256
  k_gemm_vt<<<dim3(8, 4, NB), 512, 0, stream>>>(
      WT + (size_t)2 * EMB * EMB, xb, VT, biasf + 2 * EMB);

  // 2. attention per batch-group
  for (int g = 0; g < NB; g += GB) {
    k_gemm_scores<<<dim3(8, 8, GB), 512, 0, stream>>>(QK, S, g);
    k_softmax<<<dim3(SEQ, GB), 256, 0, stream>>>(S);
    k_gemm_pv<<<dim3(4, 8, GB), 512, 0, stream>>>(S, VT, O, g);
  }

  // 3. output projection (dtype of d_out per flag): grid 256
  k_gemm_out<<<dim3(4, 64), 512, 0, stream>>>(O, WT + 3 * EMB * EMB, d_out,
                                              biasf + 3 * EMB, flag);
}

// Round 5
// 346.078 us; speedup vs baseline: 1.0992x; 1.0992x over previous
//
#include <hip/hip_runtime.h>
#include <hip/hip_fp16.h>
#include <stdint.h>

typedef unsigned short u16;
typedef __attribute__((ext_vector_type(8))) __bf16 bf16x8;
typedef __attribute__((ext_vector_type(4))) float f32x4;

#define SEQ 2048
#define EMB 768
#define NB  8
#define LDQK (2 * EMB)    // 1536: row pitch of fused Q|K buffer

// counted waits (rule #18: sched_barrier after lgkm wait so MFMA can't hoist)
#define VMCNT(n) asm volatile("s_waitcnt vmcnt(" #n ")" ::: "memory")
#define LGKM(n)                                            \
  do {                                                     \
    asm volatile("s_waitcnt lgkmcnt(" #n ")" ::: "memory"); \
    __builtin_amdgcn_sched_barrier(0);                     \
  } while (0)

__device__ __forceinline__ u16 f2bf(float f) {
  union { float f; uint32_t u; } a; a.f = f;
  uint32_t r = a.u + 0x7fffu + ((a.u >> 16) & 1u);
  return (u16)(r >> 16);
}
__device__ __forceinline__ float bf2f(u16 h) {
  union { uint32_t u; float f; } a; a.u = ((uint32_t)h) << 16;
  return a.f;
}

// Bijective XCD-aware block swizzle (T1). All GEMM grids here have nwg%8==0.
__device__ __forceinline__ void swz_bid(int& bx, int& by, int& bz)
{
  const int gx = gridDim.x, gy = gridDim.y;
  const int nwg = gx * gy * gridDim.z;
  const int lid = ((int)blockIdx.z * gy + (int)blockIdx.y) * gx +
                  (int)blockIdx.x;
  const int cpx = nwg >> 3;
  const int orig = (lid & 7) * cpx + (lid >> 3);
  bx = orig % gx;
  const int t = orig / gx;
  by = t % gy;
  bz = t / gy;
}

// ---------------------------------------------------------------------------
// dtype detect (1 = fp32 inputs) + bias conversion fused.
// ---------------------------------------------------------------------------
__global__ __launch_bounds__(256) void k_detect_bias(
    const u16* __restrict__ x, int* __restrict__ flag,
    const void* __restrict__ b0, const void* __restrict__ b1,
    const void* __restrict__ b2, const void* __restrict__ b3,
    float* __restrict__ biasf)
{
  const int tid = threadIdx.x;
  int bad = 0;
#pragma unroll
  for (int i = 0; i < 4; ++i) {
    const u16 h = x[(tid * 4 + i) * 2];
    const int e = (h >> 7) & 0xFF;
    bad += (e >= 160 && e <= 254) ? 1 : 0;
  }
#pragma unroll
  for (int off = 32; off > 0; off >>= 1) bad += __shfl_down(bad, off);
  __shared__ int cnt[4];
  __shared__ int sflag;
  if ((tid & 63) == 0) cnt[tid >> 6] = bad;
  __syncthreads();
  if (tid == 0) {
    const int f = (cnt[0] + cnt[1] + cnt[2] + cnt[3] > 200) ? 1 : 0;
    sflag = f;
    *flag = f;
  }
  __syncthreads();
  const int f32 = sflag;
#pragma unroll
  for (int z = 0; z < 4; ++z) {
    const void* src = (z == 0) ? b0 : (z == 1) ? b1 : (z == 2) ? b2 : b3;
#pragma unroll
    for (int i = 0; i < 3; ++i) {
      const int j = tid + i * 256;
      biasf[z * EMB + j] = f32 ? ((const float*)src)[j]
                               : bf2f(((const u16*)src)[j]);
    }
  }
}

__global__ __launch_bounds__(256) void k_convert_x(
    const void* __restrict__ src, u16* __restrict__ dst,
    const int* __restrict__ flag, int n4)
{
  const int i = blockIdx.x * 256 + threadIdx.x;
  if (i >= n4) return;
  if (*flag) {
    const float4 f = ((const float4*)src)[i];
    ushort4 o;
    o.x = f2bf(f.x); o.y = f2bf(f.y); o.z = f2bf(f.z); o.w = f2bf(f.w);
    ((ushort4*)dst)[i] = o;
  } else {
    ((ushort4*)dst)[i] = ((const ushort4*)src)[i];
  }
}

// weights: convert + transpose -> WT (bf16).
__global__ __launch_bounds__(256) void k_transpose_w(
    const void* __restrict__ W0, const void* __restrict__ W1,
    const void* __restrict__ W2, const void* __restrict__ W3,
    u16* __restrict__ WT, const int* __restrict__ flag)
{
  __shared__ u16 t[32][33];
  const int z = blockIdx.z;
  const void* in = (z == 0) ? W0 : (z == 1) ? W1 : (z == 2) ? W2 : W3;
  u16* out = WT + (size_t)z * EMB * EMB;
  const int c0 = blockIdx.x * 32, r0 = blockIdx.y * 32;
  const int tx = threadIdx.x, ty = threadIdx.y;
  const int f32 = *flag;
#pragma unroll
  for (int i = 0; i < 4; ++i) {
    const size_t idx = (size_t)(r0 + ty + i * 8) * EMB + c0 + tx;
    t[ty + i * 8][tx] = f32 ? f2bf(((const float*)in)[idx])
                            : ((const u16*)in)[idx];
  }
  __syncthreads();
#pragma unroll
  for (int i = 0; i < 4; ++i)
    out[(size_t)(c0 + ty + i * 8) * EMB + r0 + tx] = t[tx][ty + i * 8];
}

// ---------------------------------------------------------------------------
// 8-phase MFMA GEMM (T2+T3+T4+T5), templated tile: BM = MFR*32, BN = NFR*64.
// 512 threads = 8 waves (2M x 4N); per-wave output (MFR*16) x (NFR*16).
// BK=64, double-buffered LDS. Quarter = rows x 32 kcols bf16, linear by
// chunk (global_load_lds order), source pre-swizzled s4 ^= (row>>1)&3 and
// the same XOR on ds_read (both-sides involution).
// BALANCED ds_read schedule: the 2*(MFR+NFR) reads per K-tile are spread
// ~evenly across the 4 phases (6/6/6/6 for (8,4)) so the LDS pipe load per
// phase (~6*8waves*12cyc = 576) stays below the MFMA pipe (620) in every
// phase, instead of alternating 2/10/2/10 (960-cyc LDS spikes).
//   q3(prev): B-lo(k0) + A[0..AQ3)(k0)     [PRE reads]
//   q0:       A[AQ3..MFR)(k0) + B-hi(k0)   [MFR-AQ3+NFR-2]  -> MFMA G0
//   q1:       B-lo(k1) + A[0..AQ3)(k1)     [PRE]            -> MFMA G1
//   q2:       A[AQ3..MFR)(k1) + B-hi(k1)                    -> MFMA G2
//   q3:       vmcnt|stage|barrier|next-tile B-lo+A-lo       -> MFMA G3
// Waits: G0/G2 lgkmcnt(NFR-2) (B-hi still in flight), G1/G3 lgkmcnt(PRE).
// Configs: (8,4) 256x256, (8,3) 256x192, (6,4) 192x256.
// ---------------------------------------------------------------------------
template <int EPI, int MFR, int NFR>
__device__ __forceinline__ void gemm_core256(
    const u16* __restrict__ A, int lda,
    const u16* __restrict__ BT, int ldbt,
    void* __restrict__ Cp, int ldc,
    const float* __restrict__ biasf, const int* __restrict__ of32,
    float scale, int K, int m0, int n0)
{
  constexpr int AQ = MFR * 1024;          // u16 per A quarter (BM x 32)
  constexpr int BQ = NFR * 2048;          // u16 per B quarter (BN x 32)
  constexpr int STRIDE = 2 * AQ + 2 * BQ; // u16 per dbuf half
  constexpr int AQ3 = (MFR == 6) ? 3 : 4; // A-frags read in q3/q1 (lo group)
  constexpr int PRE = AQ3 + 2;            // reads per lo-phase (B-lo + A-lo)
  __shared__ __align__(16) u16 LDSU[2 * STRIDE];
  const int tid  = threadIdx.x;
  const int lane = tid & 63;
  const int wave = tid >> 6;
  const int wm   = wave >> 2;   // 0..1
  const int wn   = wave & 3;    // 0..3
  const int lrow = lane & 15;
  const int quad = lane >> 4;
  const int NT   = K >> 6;

  auto STAGEA = [&](int t, int kh) {
    constexpr int NCH = MFR * 128;
    const int buf = t & 1;
#pragma unroll
    for (int i = 0; i < 2; ++i) {
      const int c = i * 512 + tid;
      if (NCH == 1024 || c < NCH) {
        const int row = c >> 2;
        const int ss4 = (c & 3) ^ ((row >> 1) & 3);
        const u16* g = A + (size_t)(m0 + row) * lda + t * 64 + kh * 32 + ss4 * 8;
        u16* l = LDSU + buf * STRIDE + kh * AQ + (c & ~63) * 8;
        __builtin_amdgcn_global_load_lds(
            (const __attribute__((address_space(1))) void*)g,
            (__attribute__((address_space(3))) void*)l, 16, 0, 0);
      }
    }
  };
  auto STAGEB = [&](int t, int kh) {
    constexpr int NCH = NFR * 256;
    const int buf = t & 1;
#pragma unroll
    for (int i = 0; i < 2; ++i) {
      const int c = i * 512 + tid;
      if (NCH == 1024 || c < NCH) {
        const int row = c >> 2;
        const int ss4 = (c & 3) ^ ((row >> 1) & 3);
        const u16* g = BT + (size_t)(n0 + row) * ldbt + t * 64 + kh * 32 + ss4 * 8;
        u16* l = LDSU + buf * STRIDE + 2 * AQ + kh * BQ + (c & ~63) * 8;
        __builtin_amdgcn_global_load_lds(
            (const __attribute__((address_space(1))) void*)g,
            (__attribute__((address_space(3))) void*)l, 16, 0, 0);
      }
    }
  };

  auto FRAGA = [&](int t, int kh, int row) -> bf16x8 {
    const u16* p = LDSU + (t & 1) * STRIDE + kh * AQ + row * 32 +
                   ((quad ^ ((row >> 1) & 3)) * 8);
    bf16x8 r;
    asm volatile("ds_read_b128 %0, %1"
                 : "=v"(r)
                 : "v"((const __attribute__((address_space(3))) u16*)p));
    return r;
  };
  auto FRAGB = [&](int t, int kh, int row) -> bf16x8 {
    const u16* p = LDSU + (t & 1) * STRIDE + 2 * AQ + kh * BQ + row * 32 +
                   ((quad ^ ((row >> 1) & 3)) * 8);
    bf16x8 r;
    asm volatile("ds_read_b128 %0, %1"
                 : "=v"(r)
                 : "v"((const __attribute__((address_space(3))) u16*)p));
    return r;
  };

  f32x4 acc[MFR][NFR];
#pragma unroll
  for (int m = 0; m < MFR; ++m)
#pragma unroll
    for (int n = 0; n < NFR; ++n)
#pragma unroll
      for (int r = 0; r < 4; ++r) acc[m][n][r] = 0.0f;

  bf16x8 Af0[MFR], Af1[MFR], Bf0[NFR], Bf1[NFR];

  const int arow = wm * (MFR * 16) + lrow;
  const int brow = wn * (NFR * 16) + lrow;

  // MFMA groups: LO = n in [0,2), HI = n in [2,NFR)
  auto MG_LO = [&](bf16x8 (&Afr)[MFR], bf16x8 (&Bfr)[NFR]) {
#pragma unroll
    for (int m = 0; m < MFR; ++m)
#pragma unroll
      for (int n = 0; n < 2; ++n)
        acc[m][n] = __builtin_amdgcn_mfma_f32_16x16x32_bf16(
            Afr[m], Bfr[n], acc[m][n], 0, 0, 0);
  };
  auto MG_HI = [&](bf16x8 (&Afr)[MFR], bf16x8 (&Bfr)[NFR]) {
#pragma unroll
    for (int m = 0; m < MFR; ++m)
#pragma unroll
      for (int n = 2; n < NFR; ++n)
        acc[m][n] = __builtin_amdgcn_mfma_f32_16x16x32_bf16(
            Afr[m], Bfr[n], acc[m][n], 0, 0, 0);
  };

  // ---- prologue: stage tiles 0 and 1 fully ----
  STAGEA(0, 0); STAGEB(0, 0); STAGEA(0, 1); STAGEB(0, 1);
  STAGEA(1, 0); STAGEB(1, 0); STAGEA(1, 1); STAGEB(1, 1);
  if constexpr (MFR == 8 && NFR == 4) { VMCNT(8); } else { VMCNT(6); }
  __builtin_amdgcn_s_barrier();   // all waves' tile-0 loads landed
  // prime (mimics steady-state q3): B-lo + A[0..AQ3) of tile 0, k-half 0
  Bf0[0] = FRAGB(0, 0, brow);
  Bf0[1] = FRAGB(0, 0, brow + 16);
#pragma unroll
  for (int m = 0; m < AQ3; ++m) Af0[m] = FRAGA(0, 0, arow + m * 16);

  for (int u = 0; u < NT; ++u) {
    const bool s2 = (u + 2) < NT;
    // ---- q0: read A-hi(k0) then B-hi(k0) | stage A(u+2,0) | MFMA G0 ----
#pragma unroll
    for (int m = AQ3; m < MFR; ++m) Af0[m] = FRAGA(u, 0, arow + m * 16);
#pragma unroll
    for (int n = 2; n < NFR; ++n) Bf0[n] = FRAGB(u, 0, brow + n * 16);
    if (s2) STAGEA(u + 2, 0);
    __builtin_amdgcn_s_barrier();
    if constexpr (NFR == 3) { LGKM(1); } else { LGKM(2); }
    __builtin_amdgcn_s_setprio(1);
    MG_LO(Af0, Bf0);
    __builtin_amdgcn_s_setprio(0);
    __builtin_amdgcn_s_barrier();
    // ---- q1: read B-lo(k1) + A-lo(k1) | stage B(u+2,0) | MFMA G1 ----
    Bf1[0] = FRAGB(u, 1, brow);
    Bf1[1] = FRAGB(u, 1, brow + 16);
#pragma unroll
    for (int m = 0; m < AQ3; ++m) Af1[m] = FRAGA(u, 1, arow + m * 16);
    if (s2) STAGEB(u + 2, 0);
    __builtin_amdgcn_s_barrier();
    if constexpr (PRE == 5) { LGKM(5); } else { LGKM(6); }
    __builtin_amdgcn_s_setprio(1);
    MG_HI(Af0, Bf0);
    __builtin_amdgcn_s_setprio(0);
    __builtin_amdgcn_s_barrier();
    // ---- q2: read A-hi(k1) then B-hi(k1) | stage A(u+2,1) | MFMA G2 ----
#pragma unroll
    for (int m = AQ3; m < MFR; ++m) Af1[m] = FRAGA(u, 1, arow + m * 16);
#pragma unroll
    for (int n = 2; n < NFR; ++n) Bf1[n] = FRAGB(u, 1, brow + n * 16);
    if (s2) STAGEA(u + 2, 1);
    __builtin_amdgcn_s_barrier();
    if constexpr (NFR == 3) { LGKM(1); } else { LGKM(2); }
    __builtin_amdgcn_s_setprio(1);
    MG_LO(Af1, Bf1);
    __builtin_amdgcn_s_setprio(0);
    __builtin_amdgcn_s_barrier();
    // ---- q3: vmcnt | stage B(u+2,1) | barrier | next-tile B-lo + A-lo |
    //          MFMA G3 ----
    if (s2) {
      if constexpr (MFR == 8 && NFR == 4)      { VMCNT(6); }
      else if constexpr (MFR == 8 && NFR == 3) { VMCNT(5); }
      else                                     { VMCNT(4); }
    } else {
      VMCNT(0);
    }
    if (s2) STAGEB(u + 2, 1);
    __builtin_amdgcn_s_barrier();              // cross-wave: u+1 in LDS
    if (u + 1 < NT) {
      Bf0[0] = FRAGB(u + 1, 0, brow);
      Bf0[1] = FRAGB(u + 1, 0, brow + 16);
#pragma unroll
      for (int m = 0; m < AQ3; ++m) Af0[m] = FRAGA(u + 1, 0, arow + m * 16);
      if constexpr (PRE == 5) { LGKM(5); } else { LGKM(6); }
    } else {
      LGKM(0);
    }
    __builtin_amdgcn_s_setprio(1);
    MG_HI(Af1, Bf1);
    __builtin_amdgcn_s_setprio(0);
    __builtin_amdgcn_s_barrier();
  }

  // ---- epilogue: C/D layout col=lane&15, row=quad*4+reg ----
  const int rb = m0 + wm * (MFR * 16) + quad * 4;
  const int cb = n0 + wn * (NFR * 16) + lrow;
  if (EPI == 3) {
    u16* C = (u16*)Cp;
#pragma unroll
    for (int m = 0; m < MFR; ++m)
#pragma unroll
      for (int n = 0; n < NFR; ++n)
#pragma unroll
        for (int r = 0; r < 4; ++r) {
          const int row = rb + m * 16 + r;
          const int col = cb + n * 16;
          C[(size_t)row * ldc + col] =
              __half_as_ushort(__float2half(acc[m][n][r] * scale));
        }
  } else if (EPI == 2) {
    u16* C = (u16*)Cp;
#pragma unroll
    for (int m = 0; m < MFR; ++m)
#pragma unroll
      for (int n = 0; n < NFR; ++n)
#pragma unroll
        for (int r = 0; r < 4; ++r) {
          const int row = rb + m * 16 + r;
          const int col = cb + n * 16;
          C[(size_t)row * ldc + col] = f2bf(acc[m][n][r]);
        }
  } else if (EPI == 5) {
    u16* C = (u16*)Cp;
#pragma unroll
    for (int m = 0; m < MFR; ++m)
#pragma unroll
      for (int r = 0; r < 4; ++r) {
        const int row = rb + m * 16 + r;
        const float bv = biasf[row];
#pragma unroll
        for (int n = 0; n < NFR; ++n) {
          const int col = cb + n * 16;
          C[(size_t)row * ldc + col] = f2bf(acc[m][n][r] + bv);
        }
      }
  } else {  // EPI == 0: per-col bias, optional f32 out
    float bv[NFR];
#pragma unroll
    for (int n = 0; n < NFR; ++n) bv[n] = biasf[cb + n * 16];
    const bool f32out = (of32 != nullptr) && (*of32 != 0);
    if (f32out) {
      float* C = (float*)Cp;
#pragma unroll
      for (int m = 0; m < MFR; ++m)
#pragma unroll
        for (int n = 0; n < NFR; ++n)
#pragma unroll
          for (int r = 0; r < 4; ++r) {
            const int row = rb + m * 16 + r;
            const int col = cb + n * 16;
            C[(size_t)row * ldc + col] = acc[m][n][r] + bv[n];
          }
    } else {
      u16* C = (u16*)Cp;
#pragma unroll
      for (int m = 0; m < MFR; ++m)
#pragma unroll
        for (int n = 0; n < NFR; ++n)
#pragma unroll
          for (int r = 0; r < 4; ++r) {
            const int row = rb + m * 16 + r;
            const int col = cb + n * 16;
            C[(size_t)row * ldc + col] = f2bf(acc[m][n][r] + bv[n]);
          }
    }
  }
}

// ---- GEMM kernels --------------------------------------------------------

// Q|K projection: QK[16384][1536] = xb @ (Wq|Wk) + (bq|bk). BN=192, grid 512.
__global__ __launch_bounds__(512) void k_gemm_qk(
    const u16* __restrict__ A, const u16* __restrict__ BT,
    u16* __restrict__ QK, const float* __restrict__ biasf)
{
  int bx, by, bz; swz_bid(bx, by, bz);
  gemm_core256<0, 8, 3>(A, EMB, BT, EMB, QK, LDQK, biasf, nullptr, 1.0f, EMB,
                        by * 256, bx * 192);
}

// V^T projection: VT[b][v][seq]. BM=192 (v-dim), grid (8,4,8)=256.
__global__ __launch_bounds__(512) void k_gemm_vt(
    const u16* __restrict__ WvT, const u16* __restrict__ xb,
    u16* __restrict__ VT, const float* __restrict__ biasv)
{
  int bx, by, bz; swz_bid(bx, by, bz);
  const int b = bz;
  gemm_core256<5, 6, 4>(WvT, EMB,
                        xb + (size_t)b * SEQ * EMB, EMB,
                        VT + (size_t)b * EMB * SEQ, SEQ,
                        biasv, nullptr, 1.0f, EMB,
                        by * 192, bx * 256);
}

// output projection: d_out = O @ Wo + bo. BN=192, grid (4,64)=256.
__global__ __launch_bounds__(512) void k_gemm_out(
    const u16* __restrict__ A, const u16* __restrict__ BT,
    void* __restrict__ C, const float* __restrict__ biasf,
    const int* __restrict__ of32)
{
  int bx, by, bz; swz_bid(bx, by, bz);
  gemm_core256<0, 8, 3>(A, EMB, BT, EMB, C, EMB, biasf, of32, 1.0f, EMB,
                        by * 256, bx * 192);
}

// S[z] = Q[b] @ K[b]^T * scale  (f16 out, pitch 2048 u16). 256x256, grid 512.
__global__ __launch_bounds__(512) void k_gemm_scores(
    const u16* __restrict__ QK, u16* __restrict__ S, int b0)
{
  int bx, by, bz; swz_bid(bx, by, bz);
  const int b = b0 + bz;
  const u16* base = QK + (size_t)b * SEQ * LDQK;
  gemm_core256<3, 8, 4>(base, LDQK,              // Q
                        base + EMB, LDQK,        // K
                        S + (size_t)bz * SEQ * SEQ, SEQ,
                        nullptr, nullptr,
                        0.03608439182435161f /* 1/sqrt(768) */, EMB,
                        by * 256, bx * 256);
}

// O[b] = P[b] @ V[b]  with P bf16 (pitch 2048 u16) and VT[b] = V[b]^T.
// BN=192, grid (4,8,8)=256 = exactly 1 block/CU.
__global__ __launch_bounds__(512) void k_gemm_pv(
    const u16* __restrict__ P, const u16* __restrict__ VT,
    u16* __restrict__ O, int b0)
{
  int bx, by, bz; swz_bid(bx, by, bz);
  const int b = b0 + bz;
  gemm_core256<2, 8, 3>(P  + (size_t)bz * SEQ * SEQ, SEQ,
                        VT + (size_t)b * EMB * SEQ, SEQ,
                        O  + (size_t)b * SEQ * EMB, EMB,
                        nullptr, nullptr, 1.0f, SEQ,
                        by * 256, bx * 192);
}

// row softmax: read f16 row, write bf16 in place.
__global__ __launch_bounds__(256) void k_softmax(u16* __restrict__ S)
{
  u16* row = S + ((size_t)blockIdx.y * SEQ + blockIdx.x) * SEQ;
  const int tid = threadIdx.x;

  uint4 raw = *(const uint4*)(row + tid * 8);
  const u16* h = (const u16*)&raw;
  float v[8];
#pragma unroll
  for (int i = 0; i < 8; ++i) v[i] = __half2float(__ushort_as_half(h[i]));

  float mx = v[0];
#pragma unroll
  for (int i = 1; i < 8; ++i) mx = fmaxf(mx, v[i]);
#pragma unroll
  for (int off = 32; off > 0; off >>= 1) mx = fmaxf(mx, __shfl_down(mx, off));
  __shared__ float red[4], red2[4];
  if ((tid & 63) == 0) red[tid >> 6] = mx;
  __syncthreads();
  mx = fmaxf(fmaxf(red[0], red[1]), fmaxf(red[2], red[3]));

  float s = 0.0f;
#pragma unroll
  for (int i = 0; i < 8; ++i) { v[i] = __expf(v[i] - mx); s += v[i]; }
#pragma unroll
  for (int off = 32; off > 0; off >>= 1) s += __shfl_down(s, off);
  if ((tid & 63) == 0) red2[tid >> 6] = s;
  __syncthreads();
  s = red2[0] + red2[1] + red2[2] + red2[3];
  const float inv = 1.0f / s;

  uint4 outv;
  u16* o = (u16*)&outv;
#pragma unroll
  for (int i = 0; i < 8; ++i) o[i] = f2bf(v[i] * inv);
  *(uint4*)(row + tid * 8) = outv;
}

// ---- host launch ---------------------------------------------------------

extern "C" void kernel_launch(void* const* d_in, const int* in_sizes, int n_in,
                              void* d_out, int out_size, void* d_ws, size_t ws_size,
                              hipStream_t stream)
{
  (void)in_sizes; (void)n_in; (void)out_size;
  const void* x  = d_in[0];
  const void* Wq = d_in[1];
  const void* bq = d_in[2];
  const void* Wk = d_in[3];
  const void* bk = d_in[4];
  const void* Wv = d_in[5];
  const void* bv = d_in[6];
  const void* Wo = d_in[7];
  const void* bo = d_in[8];

  char* ws = (char*)d_ws;
  size_t off = 0;
  auto alloc = [&](size_t bytes) -> void* {
    void* p = ws + off;
    off += (bytes + 255) & ~(size_t)255;
    return p;
  };
  int*   flag  = (int*)alloc(256);
  u16*   xb    = (u16*)alloc((size_t)NB * SEQ * EMB * 2);       // 25.2 MB
  u16*   QK    = (u16*)alloc((size_t)NB * SEQ * LDQK * 2);      // 50.3 MB
  u16*   VT    = (u16*)alloc((size_t)NB * EMB * SEQ * 2);       // 25.2 MB
  u16*   O     = (u16*)alloc((size_t)NB * SEQ * EMB * 2);       // 25.2 MB
  u16*   WT    = (u16*)alloc((size_t)4 * EMB * EMB * 2);        //  4.7 MB
  float* biasf = (float*)alloc((size_t)4 * EMB * 4);
  u16*   S     = (u16*)(ws + off);                              // f16/bf16
  size_t rem   = (ws_size > off) ? ws_size - off : 0;

  int GB = 8;  // batches per S-group; shrink if workspace is tight
  while (GB > 1 && (size_t)GB * ((size_t)SEQ * SEQ * 2) > rem) GB >>= 1;

  // 0. dtype detect + bias conversion, then input normalization to bf16
  k_detect_bias<<<1, 256, 0, stream>>>((const u16*)x, flag, bq, bk, bv, bo,
                                       biasf);
  const int n4 = NB * SEQ * EMB / 4;
  k_convert_x<<<(n4 + 255) / 256, 256, 0, stream>>>(x, xb, flag, n4);
  k_transpose_w<<<dim3(EMB / 32, EMB / 32, 4), dim3(32, 8), 0, stream>>>(
      Wq, Wk, Wv, Wo, WT, flag);

  // 1a. Q|K projection (M=16384, N=1536, K=768): grid 512 = 2 full passes
  k_gemm_qk<<<dim3(8, 64), 512, 0, stream>>>(xb, WT, QK, biasf);
  // 1b. V^T projection (per batch: M=768(v), N=2048(seq), K=768): grid 256
  k_gemm_vt<<<dim3(8, 4, NB), 512, 0, stream>>>(
      WT + (size_t)2 * EMB * EMB, xb, VT, biasf + 2 * EMB);

  // 2. attention per batch-group
  for (int g = 0; g < NB; g += GB) {
    k_gemm_scores<<<dim3(8, 8, GB), 512, 0, stream>>>(QK, S, g);
    k_softmax<<<dim3(SEQ, GB), 256, 0, stream>>>(S);
    k_gemm_pv<<<dim3(4, 8, GB), 512, 0, stream>>>(S, VT, O, g);
  }

  // 3. output projection (dtype of d_out per flag): grid 256
  k_gemm_out<<<dim3(4, 64), 512, 0, stream>>>(O, WT + 3 * EMB * EMB, d_out,
                                              biasf + 3 * EMB, flag);
}